// Round 9
// baseline (87.493 us; speedup 1.0000x reference)
//
#include <hip/hip_runtime.h>
#include <hip/hip_bf16.h>

typedef __attribute__((ext_vector_type(8))) short short8;
typedef __attribute__((ext_vector_type(4))) short s16x4;
typedef __attribute__((ext_vector_type(4))) float f32x4;

#define NB_H 96
#define NB_W 128
#define NB_D 32
#define NB_C 16
#define NB_F 16
#define NPIX (2 * NB_H * NB_W)                 // 24576
#define KB2_U16 (14 * 512)                     // 7168 u16 = 14336 B
#define WS_NEED ((size_t)KB2_U16 * 2)
#define SLAB_STRIDE 1280                       // 32 rows * 40 B (32 data + 8 pad)
#define NSLAB 24                               // 4h x 6w
#define DV_OFF (NSLAB * SLAB_STRIDE)           // 30720
#define LDS_U16 ((DV_OFF + 64) / 2)

// fp32 -> bf16 RNE via intrinsic (compiler fuses pairs to v_cvt_pk_bf16_f32)
static __device__ __forceinline__ short fcvt(float f) {
  return (short)__builtin_bit_cast(unsigned short, __float2bfloat16(f));
}

// Pair table: p=3q+m (q=0..3): m=0 -> taps(6q,6q+1) [UNIF n=2q, kd=0/1];
// m=1 -> (6q+3,6q+4) [UNIF n=2q+1]; m=2 -> (6q+2,6q+5) [MIX kd=2].
// p=12 -> (24,25) [UNIF n=8]. p=13 -> (26,pad). tap t = n*3+kd.

// ---- weights prep: kern fp32 -> bf16 B-frag layout [p][grp][f][j] ---------
__global__ __launch_bounds__(256) void sconv3d_wprep(
    const float* __restrict__ kern, unsigned short* __restrict__ kb2) {
  const int i = blockIdx.x * 256 + threadIdx.x;
  if (i >= KB2_U16) return;
  const int p = i >> 9;
  const int g = (i >> 7) & 3;
  const int f = (i >> 3) & 15;
  const int j = i & 7;
  const int k = g * 8 + j;
  int lo, hi;
  if (p < 12) {
    const int q = p / 3, m = p % 3;
    lo = (m == 0) ? 6 * q : (m == 1) ? 6 * q + 3 : 6 * q + 2;
    hi = (m == 0) ? 6 * q + 1 : (m == 1) ? 6 * q + 4 : 6 * q + 5;
  } else if (p == 12) { lo = 24; hi = 25; }
  else { lo = 26; hi = -1; }
  const int t = (k < 16) ? lo : hi;
  const int c = k & 15;
  kb2[i] = (t >= 0) ? (unsigned short)fcvt(kern[(t * 16 + c) * 16 + f])
                    : (unsigned short)0;
}

// ---- fused main: 2x4-pixel tile, 512 threads, stage 24 slabs in LDS -------
__global__ __launch_bounds__(512, 8) void sconv3d_fused2(
    const float* __restrict__ img, const int* __restrict__ bp,
    const unsigned short* __restrict__ kb2, const float* __restrict__ dvp,
    float* __restrict__ out) {
  __shared__ unsigned short S[LDS_U16];
  char* Sb = (char*)S;
  const int tid = threadIdx.x;
  const int lane = tid & 63;
  const int r = lane & 15;          // A: d row; B/D: f column
  const int grp = lane >> 4;        // 0..3
  const int vc = (grp & 1) * 16;    // byte offset of c-slice within 32B row
  const int halfbit = grp >> 1;     // K half: 0 -> tap lo, 1 -> tap hi
  const int rA = r + halfbit - 1;   // depth row pre-rel, kd=(0,1) pairs
  const int rX = r + 1;             // depth row pre-rel, kd=2 pairs
  const int voff_dv = DV_OFF + vc;

  // tile decode, XCD-chunked bijective swizzle: 3072 = 8 * 384
  const int bid = (blockIdx.x & 7) * 384 + (blockIdx.x >> 3);
  const int b = bid >= (48 * 32);             // 1536 tiles per batch
  const int rem = bid - b * (48 * 32);
  const int h0 = (rem >> 5) * 2;
  const int w0 = (rem & 31) * 4;

  // ---- stage 24 slabs (4h x 6w, clamped) fp32 -> bf16 -> LDS ----
  const int t2 = tid & 127;
  const int sg = tid >> 7;                    // 0..3
  const int srow = t2 >> 2;                   // d row 0..31
  const int sb8 = (t2 & 3) * 8;               // byte offset in 32B row
#pragma unroll
  for (int pass = 0; pass < 6; ++pass) {
    const int s = pass * 4 + sg;              // slab 0..23
    const int dh = s / 6, dw = s - 6 * dh;
    const int hh = min(max(h0 + dh - 1, 0), NB_H - 1);
    const int ww = min(max(w0 + dw - 1, 0), NB_W - 1);
    const float4 v = *(const float4*)(
        img + ((b * NB_H + hh) * NB_W + ww) * (NB_D * NB_C) + t2 * 4);
    s16x4 o;
    o[0] = fcvt(v.x); o[1] = fcvt(v.y); o[2] = fcvt(v.z); o[3] = fcvt(v.w);
    *(s16x4*)(Sb + s * SLAB_STRIDE + srow * 40 + sb8) = o;
  }
  if (tid < 16) S[DV_OFF / 2 + tid] = (unsigned short)fcvt(dvp[0]);

  // ---- per-wave pixel + scalar neighbor decode ----
  const int wid = __builtin_amdgcn_readfirstlane((int)(tid >> 6));  // 0..7
  const int ph = wid >> 2, pw = wid & 3;
  const int h = h0 + ph, w = w0 + pw;
  const int pix = (b * NB_H + h) * NB_W + w;
  const int bpc = bp[pix];

#define CALCN(DI, DJ, SV, BA, RE)                                       \
  {                                                                     \
    const int hh = h + (DI), ww = w + (DJ);                             \
    SV = (hh >= 0) & (hh < NB_H) & (ww >= 0) & (ww < NB_W);             \
    const int hc = min(max(hh, 0), NB_H - 1);                           \
    const int wc = min(max(ww, 0), NB_W - 1);                           \
    RE = bpc - bp[(b * NB_H + hc) * NB_W + wc];                         \
    BA = ((ph + (DI) + 1) * 6 + pw + (DJ) + 1) * SLAB_STRIDE;           \
  }

  int sv0, ba0, re0, sv1, ba1, re1, sv2, ba2, re2, sv3, ba3, re3;
  int sv4, ba4, re4, sv5, ba5, re5, sv6, ba6, re6, sv7, ba7, re7;
  int sv8, ba8, re8;
  CALCN(-1, -1, sv0, ba0, re0);
  CALCN(-1, 0, sv1, ba1, re1);
  CALCN(-1, 1, sv2, ba2, re2);
  CALCN(0, -1, sv3, ba3, re3);
  CALCN(0, 0, sv4, ba4, re4);
  CALCN(0, 1, sv5, ba5, re5);
  CALCN(1, -1, sv6, ba6, re6);
  CALCN(1, 0, sv7, ba7, re7);
  CALCN(1, 1, sv8, ba8, re8);
#undef CALCN

  __syncthreads();

  f32x4 acc0 = {0.f, 0.f, 0.f, 0.f};  // d = 0..15
  f32x4 acc1 = {0.f, 0.f, 0.f, 0.f};  // d = 16..31

  // B-frag per pair from L1-resident kb2 (off the LDS pipe); bank-friendly
#define BFRAG(P) (*(const short8*)(kb2 + (P) * 512 + grp * 128 + r * 8))

#define PAIR_UNIF(P, SV, BA, RE)                                        \
  {                                                                     \
    const short8 bf = BFRAG(P);                                         \
    const int ds0 = rA + (RE);                                          \
    int vo0 = (BA) + ds0 * 40 + vc;                                     \
    vo0 = ((SV) && (unsigned)ds0 < NB_D) ? vo0 : voff_dv;               \
    const short8 a0 = *(const short8*)(Sb + vo0);                       \
    acc0 = __builtin_amdgcn_mfma_f32_16x16x32_bf16(a0, bf, acc0, 0, 0, 0); \
    const int ds1 = ds0 + 16;                                           \
    int vo1 = (BA) + ds1 * 40 + vc;                                     \
    vo1 = ((SV) && (unsigned)ds1 < NB_D) ? vo1 : voff_dv;               \
    const short8 a1 = *(const short8*)(Sb + vo1);                       \
    acc1 = __builtin_amdgcn_mfma_f32_16x16x32_bf16(a1, bf, acc1, 0, 0, 0); \
  }

#define PAIR_MIX(P, SVE, BAE, REE, SVO, BAO, REO)                       \
  {                                                                     \
    const short8 bf = BFRAG(P);                                         \
    const int relS = halfbit ? (REO) : (REE);                           \
    const int baS = halfbit ? (BAO) : (BAE);                            \
    const int svS = halfbit ? (SVO) : (SVE);                            \
    const int ds0 = rX + relS;                                          \
    int vo0 = baS + ds0 * 40 + vc;                                      \
    vo0 = (svS && (unsigned)ds0 < NB_D) ? vo0 : voff_dv;                \
    const short8 a0 = *(const short8*)(Sb + vo0);                       \
    acc0 = __builtin_amdgcn_mfma_f32_16x16x32_bf16(a0, bf, acc0, 0, 0, 0); \
    const int ds1 = ds0 + 16;                                           \
    int vo1 = baS + ds1 * 40 + vc;                                      \
    vo1 = (svS && (unsigned)ds1 < NB_D) ? vo1 : voff_dv;                \
    const short8 a1 = *(const short8*)(Sb + vo1);                       \
    acc1 = __builtin_amdgcn_mfma_f32_16x16x32_bf16(a1, bf, acc1, 0, 0, 0); \
  }

  // q=0: n0(-1,-1), n1(-1,0)
  PAIR_UNIF(0, sv0, ba0, re0);
  PAIR_UNIF(1, sv1, ba1, re1);
  PAIR_MIX(2, sv0, ba0, re0, sv1, ba1, re1);
  // q=1: n2(-1,+1), n3(0,-1)
  PAIR_UNIF(3, sv2, ba2, re2);
  PAIR_UNIF(4, sv3, ba3, re3);
  PAIR_MIX(5, sv2, ba2, re2, sv3, ba3, re3);
  // q=2: n4(0,0), n5(0,+1)
  PAIR_UNIF(6, sv4, ba4, re4);
  PAIR_UNIF(7, sv5, ba5, re5);
  PAIR_MIX(8, sv4, ba4, re4, sv5, ba5, re5);
  // q=3: n6(+1,-1), n7(+1,0)
  PAIR_UNIF(9, sv6, ba6, re6);
  PAIR_UNIF(10, sv7, ba7, re7);
  PAIR_MIX(11, sv6, ba6, re6, sv7, ba7, re7);
  // n8(+1,+1)
  PAIR_UNIF(12, sv8, ba8, re8);
  PAIR_MIX(13, sv8, ba8, re8, 0, ba8, re8);

#undef PAIR_UNIF
#undef PAIR_MIX
#undef BFRAG

  // D layout: col = lane&15 (=f), row = grp*4 + reg
  const int obase = pix * (NB_D * NB_F);
#pragma unroll
  for (int rr = 0; rr < 4; ++rr) {
    out[obase + (grp * 4 + rr) * NB_F + r] = acc0[rr];
    out[obase + (grp * 4 + rr + 16) * NB_F + r] = acc1[rr];
  }
}

// ---------------- fallback (self-contained) if ws is too small -------------
__global__ __launch_bounds__(256) void sconv3d_mfma(
    const float* __restrict__ img, const int* __restrict__ bp,
    const float* __restrict__ kern, const float* __restrict__ dvp,
    float* __restrict__ out, int npix) {
  __shared__ unsigned short Kb[28 * 256];
  const int tid = threadIdx.x;
  for (int idx = tid; idx < 28 * 256; idx += 256) {
    unsigned short v = 0;
    if (idx < 27 * 256) v = (unsigned short)fcvt(kern[idx]);
    Kb[idx] = v;
  }
  __syncthreads();

  const int lane = tid & 63;
  const int grp = lane >> 4;
  const int r = lane & 15;
  const int c0 = (grp & 1) * 8;
  const int half = grp >> 1;

  short8 bfrag[14];
#pragma unroll
  for (int p = 0; p < 14; ++p) {
#pragma unroll
    for (int j = 0; j < 8; ++j) {
      const int k = 8 * grp + j;
      const int t = 2 * p + (k >> 4);
      bfrag[p][j] = (short)Kb[t * 256 + (k & 15) * 16 + r];
    }
  }

  const int pix = blockIdx.x * 4 + (tid >> 6);
  if (pix >= npix) return;
  const int b = pix / (NB_H * NB_W);
  const int rem = pix - b * (NB_H * NB_W);
  const int h = rem >> 7;
  const int w = rem & (NB_W - 1);

  const float dv = dvp[0];
  const int bpc = bp[pix];

  f32x4 acc0 = {0.f, 0.f, 0.f, 0.f};
  f32x4 acc1 = {0.f, 0.f, 0.f, 0.f};

#pragma unroll
  for (int p = 0; p < 14; ++p) {
    const int t = 2 * p + half;
    const int n = t / 3;
    const int kd = t - 3 * n;
    const int i = n / 3;
    const int j = n - 3 * i;
    const int hh = h + i - 1;
    const int ww = w + j - 1;
    const bool sv =
        (t < 27) && (hh >= 0) && (hh < NB_H) && (ww >= 0) && (ww < NB_W);
    const int hc = min(max(hh, 0), NB_H - 1);
    const int wc = min(max(ww, 0), NB_W - 1);
    const int nidx = (b * NB_H + hc) * NB_W + wc;
    const int rel = bpc - bp[nidx];
    const int base = nidx * (NB_D * NB_C);
    const int dsh = (kd - 1) + rel;

    const int ds0 = r + dsh;
    short8 a0;
    {
      float va[8];
      if (sv && (ds0 >= 0) && (ds0 < NB_D)) {
        const float4* pp = (const float4*)(img + base + ds0 * NB_C + c0);
        const float4 x = pp[0];
        const float4 y = pp[1];
        va[0] = x.x; va[1] = x.y; va[2] = x.z; va[3] = x.w;
        va[4] = y.x; va[5] = y.y; va[6] = y.z; va[7] = y.w;
      } else {
#pragma unroll
        for (int q = 0; q < 8; ++q) va[q] = dv;
      }
#pragma unroll
      for (int q = 0; q < 8; ++q) a0[q] = fcvt(va[q]);
    }
    acc0 = __builtin_amdgcn_mfma_f32_16x16x32_bf16(a0, bfrag[p], acc0, 0, 0, 0);

    const int ds1 = ds0 + 16;
    short8 a1;
    {
      float va[8];
      if (sv && (ds1 >= 0) && (ds1 < NB_D)) {
        const float4* pp = (const float4*)(img + base + ds1 * NB_C + c0);
        const float4 x = pp[0];
        const float4 y = pp[1];
        va[0] = x.x; va[1] = x.y; va[2] = x.z; va[3] = x.w;
        va[4] = y.x; va[5] = y.y; va[6] = y.z; va[7] = y.w;
      } else {
#pragma unroll
        for (int q = 0; q < 8; ++q) va[q] = dv;
      }
#pragma unroll
      for (int q = 0; q < 8; ++q) a1[q] = fcvt(va[q]);
    }
    acc1 = __builtin_amdgcn_mfma_f32_16x16x32_bf16(a1, bfrag[p], acc1, 0, 0, 0);
  }

  const int obase = pix * (NB_D * NB_F);
#pragma unroll
  for (int rr = 0; rr < 4; ++rr) {
    out[obase + (grp * 4 + rr) * NB_F + r] = acc0[rr];
    out[obase + (grp * 4 + rr + 16) * NB_F + r] = acc1[rr];
  }
}

extern "C" void kernel_launch(void* const* d_in, const int* in_sizes, int n_in,
                              void* d_out, int out_size, void* d_ws, size_t ws_size,
                              hipStream_t stream) {
  const float* img = (const float*)d_in[0];
  const int* bp = (const int*)d_in[1];
  const float* kern = (const float*)d_in[2];
  const float* dvp = (const float*)d_in[3];
  float* out = (float*)d_out;

  if (ws_size >= WS_NEED) {
    unsigned short* kb2 = (unsigned short*)d_ws;
    sconv3d_wprep<<<28, 256, 0, stream>>>(kern, kb2);
    sconv3d_fused2<<<NPIX / 8, 512, 0, stream>>>(img, bp, kb2, dvp, out);
  } else {
    sconv3d_mfma<<<NPIX / 4, 256, 0, stream>>>(img, bp, kern, dvp, out, NPIX);
  }
}

// Round 10
// 49.524 us; speedup vs baseline: 1.7667x; 1.7667x over previous
//
#include <hip/hip_runtime.h>
#include <hip/hip_bf16.h>

typedef __attribute__((ext_vector_type(8))) short short8;
typedef __attribute__((ext_vector_type(4))) short s16x4;
typedef __attribute__((ext_vector_type(4))) float f32x4;
typedef __attribute__((ext_vector_type(4))) int i32x4;

#define NB_H 96
#define NB_W 128
#define NB_D 32
#define NB_C 16
#define NB_F 16
#define NPIX (2 * NB_H * NB_W)                 // 24576
#define KB2_U16 (14 * 512)                     // 7168 u16 = 14336 B
#define WS_NEED ((size_t)KB2_U16 * 2)
#define SLAB_STRIDE 1280                       // 32 rows * 40 B (32 data + 8 pad)
#define NSLAB 36                               // 6h x 6w (4x4 pixel tile + halo)
#define DV_OFF (NSLAB * SLAB_STRIDE)           // 46080
#define KB_OFF (DV_OFF + 64)                   // 46144
#define LDS_BYTES (KB_OFF + KB2_U16 * 2)       // 60480

// fp32 -> bf16 RNE
static __device__ __forceinline__ short fcvt(float f) {
  return (short)__builtin_bit_cast(unsigned short, __float2bfloat16(f));
}

// Pair table: p=3q+m (q=0..3): m=0 -> taps(6q,6q+1) [UNIF n=2q, kd=0/1];
// m=1 -> (6q+3,6q+4) [UNIF n=2q+1]; m=2 -> (6q+2,6q+5) [MIX kd=2].
// p=12 -> (24,25) [UNIF n=8]. p=13 -> (26,pad). tap t = n*3+kd.

// ---- weights prep: kern fp32 -> bf16 B-frag layout [p][grp][f][j] ---------
__global__ __launch_bounds__(256) void sconv3d_wprep(
    const float* __restrict__ kern, unsigned short* __restrict__ kb2) {
  const int i = blockIdx.x * 256 + threadIdx.x;
  if (i >= KB2_U16) return;
  const int p = i >> 9;
  const int g = (i >> 7) & 3;
  const int f = (i >> 3) & 15;
  const int j = i & 7;
  const int k = g * 8 + j;
  int lo, hi;
  if (p < 12) {
    const int q = p / 3, m = p % 3;
    lo = (m == 0) ? 6 * q : (m == 1) ? 6 * q + 3 : 6 * q + 2;
    hi = (m == 0) ? 6 * q + 1 : (m == 1) ? 6 * q + 4 : 6 * q + 5;
  } else if (p == 12) { lo = 24; hi = 25; }
  else { lo = 26; hi = -1; }
  const int t = (k < 16) ? lo : hi;
  const int c = k & 15;
  kb2[i] = (t >= 0) ? (unsigned short)fcvt(kern[(t * 16 + c) * 16 + f])
                    : (unsigned short)0;
}

// ---- fused main: 4x4-pixel tile, 512 threads, 2 px/wave -------------------
__global__ __launch_bounds__(512, 4) void sconv3d_fused3(
    const float* __restrict__ img, const int* __restrict__ bp,
    const unsigned short* __restrict__ kb2, const float* __restrict__ dvp,
    float* __restrict__ out) {
  __shared__ char Sb[LDS_BYTES];
  const int tid = threadIdx.x;
  const int lane = tid & 63;
  const int r = lane & 15;          // A: d row; B/D: f column
  const int grp = lane >> 4;        // 0..3
  const int vc = (grp & 1) * 16;    // byte offset of c-slice within 32B row
  const int halfbit = grp >> 1;     // K half: 0 -> tap lo, 1 -> tap hi
  const int rA = r + halfbit - 1;   // depth row pre-rel, kd=(0,1) pairs
  const int rX = r + 1;             // depth row pre-rel, kd=2 pairs
  const int voff_dv = DV_OFF + vc;

  // stage B-frags to LDS (14336 B)
  {
    const i32x4* src = (const i32x4*)kb2;
    i32x4* dst = (i32x4*)(Sb + KB_OFF);
    for (int i = tid; i < (KB2_U16 * 2) / 16; i += 512) dst[i] = src[i];
  }
  if (tid < 16) ((unsigned short*)(Sb + DV_OFF))[tid] =
      (unsigned short)fcvt(dvp[0]);

  // tile decode, XCD-chunked bijective swizzle: 1536 = 8 * 192
  const int bid = (blockIdx.x & 7) * 192 + (blockIdx.x >> 3);
  const int b = bid >= 768;                   // 768 tiles per batch
  const int rem = bid - b * 768;
  const int h0 = (rem >> 5) * 4;              // 24 h-tiles
  const int w0 = (rem & 31) * 4;              // 32 w-tiles

  // ---- stage 36 slabs (6h x 6w, clamped) fp32 -> bf16 -> LDS ----
  const int t2 = tid & 127;
  const int sg = tid >> 7;                    // 0..3
  const int srow = t2 >> 2;                   // d row 0..31
  const int sb8 = (t2 & 3) * 8;               // byte offset in 32B row
#pragma unroll
  for (int pass = 0; pass < 9; ++pass) {
    const int s = pass * 4 + sg;              // slab 0..35
    const int dh = s / 6, dw = s - 6 * dh;
    const int hh = min(max(h0 + dh - 1, 0), NB_H - 1);
    const int ww = min(max(w0 + dw - 1, 0), NB_W - 1);
    const float4 v = *(const float4*)(
        img + ((b * NB_H + hh) * NB_W + ww) * (NB_D * NB_C) + t2 * 4);
    s16x4 o;
    o[0] = fcvt(v.x); o[1] = fcvt(v.y); o[2] = fcvt(v.z); o[3] = fcvt(v.w);
    *(s16x4*)(Sb + s * SLAB_STRIDE + srow * 40 + sb8) = o;
  }

  // ---- per-wave: two pixels (rows phA, phA+2 of the tile; shared column) --
  const int wid = __builtin_amdgcn_readfirstlane((int)(tid >> 6));  // 0..7
  const int pw = wid & 3;
  const int phA = wid >> 2;                   // 0..1
  const int phB = phA + 2;                    // 2..3
  const int hA = h0 + phA, hB = h0 + phB, w = w0 + pw;
  const int pixA = (b * NB_H + hA) * NB_W + w;
  const int pixB = (b * NB_H + hB) * NB_W + w;
  const int bpcA = bp[pixA];
  const int bpcB = bp[pixB];

#define CALCN(PH, H, BPC, DI, DJ, SV, BA, RE)                           \
  {                                                                     \
    const int hh = (H) + (DI), ww = w + (DJ);                           \
    SV = (hh >= 0) & (hh < NB_H) & (ww >= 0) & (ww < NB_W);             \
    const int hc = min(max(hh, 0), NB_H - 1);                           \
    const int wc = min(max(ww, 0), NB_W - 1);                           \
    RE = (BPC)-bp[(b * NB_H + hc) * NB_W + wc];                         \
    BA = (((PH) + (DI) + 1) * 6 + pw + (DJ) + 1) * SLAB_STRIDE;         \
  }

  int Asv0, Aba0, Are0, Asv1, Aba1, Are1, Asv2, Aba2, Are2;
  int Asv3, Aba3, Are3, Asv4, Aba4, Are4, Asv5, Aba5, Are5;
  int Asv6, Aba6, Are6, Asv7, Aba7, Are7, Asv8, Aba8, Are8;
  int Bsv0, Bba0, Bre0, Bsv1, Bba1, Bre1, Bsv2, Bba2, Bre2;
  int Bsv3, Bba3, Bre3, Bsv4, Bba4, Bre4, Bsv5, Bba5, Bre5;
  int Bsv6, Bba6, Bre6, Bsv7, Bba7, Bre7, Bsv8, Bba8, Bre8;
  CALCN(phA, hA, bpcA, -1, -1, Asv0, Aba0, Are0);
  CALCN(phA, hA, bpcA, -1, 0, Asv1, Aba1, Are1);
  CALCN(phA, hA, bpcA, -1, 1, Asv2, Aba2, Are2);
  CALCN(phA, hA, bpcA, 0, -1, Asv3, Aba3, Are3);
  CALCN(phA, hA, bpcA, 0, 0, Asv4, Aba4, Are4);
  CALCN(phA, hA, bpcA, 0, 1, Asv5, Aba5, Are5);
  CALCN(phA, hA, bpcA, 1, -1, Asv6, Aba6, Are6);
  CALCN(phA, hA, bpcA, 1, 0, Asv7, Aba7, Are7);
  CALCN(phA, hA, bpcA, 1, 1, Asv8, Aba8, Are8);
  CALCN(phB, hB, bpcB, -1, -1, Bsv0, Bba0, Bre0);
  CALCN(phB, hB, bpcB, -1, 0, Bsv1, Bba1, Bre1);
  CALCN(phB, hB, bpcB, -1, 1, Bsv2, Bba2, Bre2);
  CALCN(phB, hB, bpcB, 0, -1, Bsv3, Bba3, Bre3);
  CALCN(phB, hB, bpcB, 0, 0, Bsv4, Bba4, Bre4);
  CALCN(phB, hB, bpcB, 0, 1, Bsv5, Bba5, Bre5);
  CALCN(phB, hB, bpcB, 1, -1, Bsv6, Bba6, Bre6);
  CALCN(phB, hB, bpcB, 1, 0, Bsv7, Bba7, Bre7);
  CALCN(phB, hB, bpcB, 1, 1, Bsv8, Bba8, Bre8);
#undef CALCN

  __syncthreads();

  f32x4 accA0 = {0.f, 0.f, 0.f, 0.f}, accA1 = {0.f, 0.f, 0.f, 0.f};
  f32x4 accB0 = {0.f, 0.f, 0.f, 0.f}, accB1 = {0.f, 0.f, 0.f, 0.f};

  // one half-pixel: 2 LDS A-reads + 2 MFMAs, dv-offset redirect
#define HALF(P, ROWBASE, SV, BA, RE, AC0, AC1, BF)                      \
  {                                                                     \
    const int ds0 = (ROWBASE) + (RE);                                   \
    int vo0 = (BA) + ds0 * 40 + vc;                                     \
    vo0 = ((SV) && (unsigned)ds0 < NB_D) ? vo0 : voff_dv;               \
    const short8 a0 = *(const short8*)(Sb + vo0);                       \
    AC0 = __builtin_amdgcn_mfma_f32_16x16x32_bf16(a0, BF, AC0, 0, 0, 0); \
    const int ds1 = ds0 + 16;                                           \
    int vo1 = (BA) + ds1 * 40 + vc;                                     \
    vo1 = ((SV) && (unsigned)ds1 < NB_D) ? vo1 : voff_dv;               \
    const short8 a1 = *(const short8*)(Sb + vo1);                       \
    AC1 = __builtin_amdgcn_mfma_f32_16x16x32_bf16(a1, BF, AC1, 0, 0, 0); \
  }

#define PAIR_UNIF(P, N)                                                 \
  {                                                                     \
    const short8 bf = *(const short8*)(Sb + KB_OFF + (P) * 1024 +       \
                                       grp * 256 + r * 16);             \
    HALF(P, rA, Asv##N, Aba##N, Are##N, accA0, accA1, bf);              \
    HALF(P, rA, Bsv##N, Bba##N, Bre##N, accB0, accB1, bf);              \
  }

#define PAIR_MIX(P, NE, NO)                                             \
  {                                                                     \
    const short8 bf = *(const short8*)(Sb + KB_OFF + (P) * 1024 +       \
                                       grp * 256 + r * 16);             \
    const int AsvS = halfbit ? Asv##NO : Asv##NE;                       \
    const int AbaS = halfbit ? Aba##NO : Aba##NE;                       \
    const int AreS = halfbit ? Are##NO : Are##NE;                       \
    HALF(P, rX, AsvS, AbaS, AreS, accA0, accA1, bf);                    \
    const int BsvS = halfbit ? Bsv##NO : Bsv##NE;                       \
    const int BbaS = halfbit ? Bba##NO : Bba##NE;                       \
    const int BreS = halfbit ? Bre##NO : Bre##NE;                       \
    HALF(P, rX, BsvS, BbaS, BreS, accB0, accB1, bf);                    \
  }

#define PAIR_MIX13(P, NE)                                               \
  {                                                                     \
    const short8 bf = *(const short8*)(Sb + KB_OFF + (P) * 1024 +       \
                                       grp * 256 + r * 16);             \
    const int AsvS = halfbit ? 0 : Asv##NE;                             \
    const int AbaS = Aba##NE;                                           \
    const int AreS = Are##NE;                                           \
    HALF(P, rX, AsvS, AbaS, AreS, accA0, accA1, bf);                    \
    const int BsvS = halfbit ? 0 : Bsv##NE;                             \
    const int BbaS = Bba##NE;                                           \
    const int BreS = Bre##NE;                                           \
    HALF(P, rX, BsvS, BbaS, BreS, accB0, accB1, bf);                    \
  }

  PAIR_UNIF(0, 0);
  PAIR_UNIF(1, 1);
  PAIR_MIX(2, 0, 1);
  PAIR_UNIF(3, 2);
  PAIR_UNIF(4, 3);
  PAIR_MIX(5, 2, 3);
  PAIR_UNIF(6, 4);
  PAIR_UNIF(7, 5);
  PAIR_MIX(8, 4, 5);
  PAIR_UNIF(9, 6);
  PAIR_UNIF(10, 7);
  PAIR_MIX(11, 6, 7);
  PAIR_UNIF(12, 8);
  PAIR_MIX13(13, 8);

#undef HALF
#undef PAIR_UNIF
#undef PAIR_MIX
#undef PAIR_MIX13

  // D layout: col = lane&15 (=f), row = grp*4 + reg
  const int obaseA = pixA * (NB_D * NB_F);
  const int obaseB = pixB * (NB_D * NB_F);
#pragma unroll
  for (int rr = 0; rr < 4; ++rr) {
    out[obaseA + (grp * 4 + rr) * NB_F + r] = accA0[rr];
    out[obaseA + (grp * 4 + rr + 16) * NB_F + r] = accA1[rr];
    out[obaseB + (grp * 4 + rr) * NB_F + r] = accB0[rr];
    out[obaseB + (grp * 4 + rr + 16) * NB_F + r] = accB1[rr];
  }
}

// ---------------- fallback (self-contained) if ws is too small -------------
__global__ __launch_bounds__(256) void sconv3d_mfma(
    const float* __restrict__ img, const int* __restrict__ bp,
    const float* __restrict__ kern, const float* __restrict__ dvp,
    float* __restrict__ out, int npix) {
  __shared__ unsigned short Kb[28 * 256];
  const int tid = threadIdx.x;
  for (int idx = tid; idx < 28 * 256; idx += 256) {
    unsigned short v = 0;
    if (idx < 27 * 256) v = (unsigned short)fcvt(kern[idx]);
    Kb[idx] = v;
  }
  __syncthreads();

  const int lane = tid & 63;
  const int grp = lane >> 4;
  const int r = lane & 15;
  const int c0 = (grp & 1) * 8;
  const int half = grp >> 1;

  short8 bfrag[14];
#pragma unroll
  for (int p = 0; p < 14; ++p) {
#pragma unroll
    for (int j = 0; j < 8; ++j) {
      const int k = 8 * grp + j;
      const int t = 2 * p + (k >> 4);
      bfrag[p][j] = (short)Kb[t * 256 + (k & 15) * 16 + r];
    }
  }

  const int pix = blockIdx.x * 4 + (tid >> 6);
  if (pix >= npix) return;
  const int b = pix / (NB_H * NB_W);
  const int rem = pix - b * (NB_H * NB_W);
  const int h = rem >> 7;
  const int w = rem & (NB_W - 1);

  const float dv = dvp[0];
  const int bpc = bp[pix];

  f32x4 acc0 = {0.f, 0.f, 0.f, 0.f};
  f32x4 acc1 = {0.f, 0.f, 0.f, 0.f};

#pragma unroll
  for (int p = 0; p < 14; ++p) {
    const int t = 2 * p + half;
    const int n = t / 3;
    const int kd = t - 3 * n;
    const int i = n / 3;
    const int j = n - 3 * i;
    const int hh = h + i - 1;
    const int ww = w + j - 1;
    const bool sv =
        (t < 27) && (hh >= 0) && (hh < NB_H) && (ww >= 0) && (ww < NB_W);
    const int hc = min(max(hh, 0), NB_H - 1);
    const int wc = min(max(ww, 0), NB_W - 1);
    const int nidx = (b * NB_H + hc) * NB_W + wc;
    const int rel = bpc - bp[nidx];
    const int base = nidx * (NB_D * NB_C);
    const int dsh = (kd - 1) + rel;

    const int ds0 = r + dsh;
    short8 a0;
    {
      float va[8];
      if (sv && (ds0 >= 0) && (ds0 < NB_D)) {
        const float4* pp = (const float4*)(img + base + ds0 * NB_C + c0);
        const float4 x = pp[0];
        const float4 y = pp[1];
        va[0] = x.x; va[1] = x.y; va[2] = x.z; va[3] = x.w;
        va[4] = y.x; va[5] = y.y; va[6] = y.z; va[7] = y.w;
      } else {
#pragma unroll
        for (int q = 0; q < 8; ++q) va[q] = dv;
      }
#pragma unroll
      for (int q = 0; q < 8; ++q) a0[q] = fcvt(va[q]);
    }
    acc0 = __builtin_amdgcn_mfma_f32_16x16x32_bf16(a0, bfrag[p], acc0, 0, 0, 0);

    const int ds1 = ds0 + 16;
    short8 a1;
    {
      float va[8];
      if (sv && (ds1 >= 0) && (ds1 < NB_D)) {
        const float4* pp = (const float4*)(img + base + ds1 * NB_C + c0);
        const float4 x = pp[0];
        const float4 y = pp[1];
        va[0] = x.x; va[1] = x.y; va[2] = x.z; va[3] = x.w;
        va[4] = y.x; va[5] = y.y; va[6] = y.z; va[7] = y.w;
      } else {
#pragma unroll
        for (int q = 0; q < 8; ++q) va[q] = dv;
      }
#pragma unroll
      for (int q = 0; q < 8; ++q) a1[q] = fcvt(va[q]);
    }
    acc1 = __builtin_amdgcn_mfma_f32_16x16x32_bf16(a1, bfrag[p], acc1, 0, 0, 0);
  }

  const int obase = pix * (NB_D * NB_F);
#pragma unroll
  for (int rr = 0; rr < 4; ++rr) {
    out[obase + (grp * 4 + rr) * NB_F + r] = acc0[rr];
    out[obase + (grp * 4 + rr + 16) * NB_F + r] = acc1[rr];
  }
}

extern "C" void kernel_launch(void* const* d_in, const int* in_sizes, int n_in,
                              void* d_out, int out_size, void* d_ws, size_t ws_size,
                              hipStream_t stream) {
  const float* img = (const float*)d_in[0];
  const int* bp = (const int*)d_in[1];
  const float* kern = (const float*)d_in[2];
  const float* dvp = (const float*)d_in[3];
  float* out = (float*)d_out;

  if (ws_size >= WS_NEED) {
    unsigned short* kb2 = (unsigned short*)d_ws;
    sconv3d_wprep<<<28, 256, 0, stream>>>(kern, kb2);
    sconv3d_fused3<<<NPIX / 16, 512, 0, stream>>>(img, bp, kb2, dvp, out);
  } else {
    sconv3d_mfma<<<NPIX / 4, 256, 0, stream>>>(img, bp, kern, dvp, out, NPIX);
  }
}

// Round 11
// 47.167 us; speedup vs baseline: 1.8550x; 1.0500x over previous
//
#include <hip/hip_runtime.h>
#include <hip/hip_bf16.h>

typedef __attribute__((ext_vector_type(8))) short short8;
typedef __attribute__((ext_vector_type(4))) short s16x4;
typedef __attribute__((ext_vector_type(4))) float f32x4;

#define NB_H 96
#define NB_W 128
#define NB_D 32
#define NB_C 16
#define NB_F 16
#define NPIX (2 * NB_H * NB_W)                 // 24576
#define KB2_U16 (14 * 512)                     // 7168 u16 = 14336 B
#define WS_NEED ((size_t)KB2_U16 * 2)
#define SLAB_STRIDE 1280                       // 32 rows * 40 B (32 data + 8 pad)
#define NSLAB 24                               // 4h x 6w (2x4 pixel tile + halo)
#define DV_OFF (NSLAB * SLAB_STRIDE)           // 30720
#define LDS_BYTES (DV_OFF + 64)                // 30784

// fp32 -> bf16 RNE
static __device__ __forceinline__ short fcvt(float f) {
  return (short)__builtin_bit_cast(unsigned short, __float2bfloat16(f));
}

// Pair table: p=3q+m (q=0..3): m=0 -> taps(6q,6q+1) [UNIF n=2q, kd=0/1];
// m=1 -> (6q+3,6q+4) [UNIF n=2q+1]; m=2 -> (6q+2,6q+5) [MIX kd=2].
// p=12 -> (24,25) [UNIF n=8]. p=13 -> (26,pad). tap t = n*3+kd.

// ---- weights prep: kern fp32 -> bf16 B-frag layout [p][grp][f][j] ---------
__global__ __launch_bounds__(256) void sconv3d_wprep(
    const float* __restrict__ kern, unsigned short* __restrict__ kb2) {
  const int i = blockIdx.x * 256 + threadIdx.x;
  if (i >= KB2_U16) return;
  const int p = i >> 9;
  const int g = (i >> 7) & 3;
  const int f = (i >> 3) & 15;
  const int j = i & 7;
  const int k = g * 8 + j;
  int lo, hi;
  if (p < 12) {
    const int q = p / 3, m = p % 3;
    lo = (m == 0) ? 6 * q : (m == 1) ? 6 * q + 3 : 6 * q + 2;
    hi = (m == 0) ? 6 * q + 1 : (m == 1) ? 6 * q + 4 : 6 * q + 5;
  } else if (p == 12) { lo = 24; hi = 25; }
  else { lo = 26; hi = -1; }
  const int t = (k < 16) ? lo : hi;
  const int c = k & 15;
  kb2[i] = (t >= 0) ? (unsigned short)fcvt(kern[(t * 16 + c) * 16 + f])
                    : (unsigned short)0;
}

// ---- fused main: 2x4-px tile, 256 threads, 2 px/wave, pipelined LDS reads -
__global__ __launch_bounds__(256, 4) void sconv3d_fused4(
    const float* __restrict__ img, const int* __restrict__ bp,
    const unsigned short* __restrict__ kb2, const float* __restrict__ dvp,
    float* __restrict__ out) {
  __shared__ char Sb[LDS_BYTES];
  const int tid = threadIdx.x;
  const int lane = tid & 63;
  const int r = lane & 15;          // A: d row; B/D: f column
  const int grp = lane >> 4;        // 0..3
  const int vc = (grp & 1) * 16;    // byte offset of c-slice within 32B row
  const int halfbit = grp >> 1;     // K half: 0 -> tap lo, 1 -> tap hi
  const int rA = r + halfbit - 1;   // depth row pre-rel, kd=(0,1) pairs
  const int rX = r + 1;             // depth row pre-rel, kd=2 pairs
  const int voff_dv = DV_OFF + vc;

  // B-frags: 14 global loads issued first (drain under staging waits)
  short8 bfrag[14];
#pragma unroll
  for (int p = 0; p < 14; ++p)
    bfrag[p] = *(const short8*)(kb2 + p * 512 + grp * 128 + r * 8);

  // tile decode, XCD-chunked bijective swizzle: 3072 = 8 * 384
  const int bid = (blockIdx.x & 7) * 384 + (blockIdx.x >> 3);
  const int b = bid >= 1536;                  // 1536 tiles per batch
  const int rem = bid - b * 1536;
  const int h0 = (rem >> 5) * 2;              // 48 h-tiles
  const int w0 = (rem & 31) * 4;              // 32 w-tiles

  // ---- stage 24 slabs (4h x 6w, clamped) fp32 -> bf16 -> LDS ----
  const int t2 = tid & 127;
  const int sg = tid >> 7;                    // 0..1
  const int srow = t2 >> 2;                   // d row 0..31
  const int sb8 = (t2 & 3) * 8;               // byte offset in 32B row
#pragma unroll
  for (int pass = 0; pass < 12; ++pass) {
    const int s = pass * 2 + sg;              // slab 0..23
    const int dh = s / 6, dw = s - 6 * dh;
    const int hh = min(max(h0 + dh - 1, 0), NB_H - 1);
    const int ww = min(max(w0 + dw - 1, 0), NB_W - 1);
    const float4 v = *(const float4*)(
        img + ((b * NB_H + hh) * NB_W + ww) * (NB_D * NB_C) + t2 * 4);
    s16x4 o;
    o[0] = fcvt(v.x); o[1] = fcvt(v.y); o[2] = fcvt(v.z); o[3] = fcvt(v.w);
    *(s16x4*)(Sb + s * SLAB_STRIDE + srow * 40 + sb8) = o;
  }
  if (tid < 16) ((unsigned short*)(Sb + DV_OFF))[tid] =
      (unsigned short)fcvt(dvp[0]);

  // ---- per-wave: pixels (h0, w0+wid) and (h0+1, w0+wid) ----
  const int wid = __builtin_amdgcn_readfirstlane((int)(tid >> 6));  // 0..3
  const int w = w0 + wid;
  const int hA = h0, hB = h0 + 1;
  const int pixA = (b * NB_H + hA) * NB_W + w;
  const int pixB = pixA + NB_W;
  const int bpcA = bp[pixA];
  const int bpcB = bp[pixB];

#define CALCN(PH, H, BPC, DI, DJ, SV, BA, RE)                           \
  {                                                                     \
    const int hh = (H) + (DI), ww = w + (DJ);                           \
    SV = (hh >= 0) & (hh < NB_H) & (ww >= 0) & (ww < NB_W);             \
    const int hc = min(max(hh, 0), NB_H - 1);                           \
    const int wc = min(max(ww, 0), NB_W - 1);                           \
    RE = (BPC)-bp[(b * NB_H + hc) * NB_W + wc];                         \
    BA = (((PH) + (DI) + 1) * 6 + wid + (DJ) + 1) * SLAB_STRIDE;        \
  }

  int Asv0, Aba0, Are0, Asv1, Aba1, Are1, Asv2, Aba2, Are2;
  int Asv3, Aba3, Are3, Asv4, Aba4, Are4, Asv5, Aba5, Are5;
  int Asv6, Aba6, Are6, Asv7, Aba7, Are7, Asv8, Aba8, Are8;
  int Bsv0, Bba0, Bre0, Bsv1, Bba1, Bre1, Bsv2, Bba2, Bre2;
  int Bsv3, Bba3, Bre3, Bsv4, Bba4, Bre4, Bsv5, Bba5, Bre5;
  int Bsv6, Bba6, Bre6, Bsv7, Bba7, Bre7, Bsv8, Bba8, Bre8;
  CALCN(0, hA, bpcA, -1, -1, Asv0, Aba0, Are0);
  CALCN(0, hA, bpcA, -1, 0, Asv1, Aba1, Are1);
  CALCN(0, hA, bpcA, -1, 1, Asv2, Aba2, Are2);
  CALCN(0, hA, bpcA, 0, -1, Asv3, Aba3, Are3);
  CALCN(0, hA, bpcA, 0, 0, Asv4, Aba4, Are4);
  CALCN(0, hA, bpcA, 0, 1, Asv5, Aba5, Are5);
  CALCN(0, hA, bpcA, 1, -1, Asv6, Aba6, Are6);
  CALCN(0, hA, bpcA, 1, 0, Asv7, Aba7, Are7);
  CALCN(0, hA, bpcA, 1, 1, Asv8, Aba8, Are8);
  CALCN(1, hB, bpcB, -1, -1, Bsv0, Bba0, Bre0);
  CALCN(1, hB, bpcB, -1, 0, Bsv1, Bba1, Bre1);
  CALCN(1, hB, bpcB, -1, 1, Bsv2, Bba2, Bre2);
  CALCN(1, hB, bpcB, 0, -1, Bsv3, Bba3, Bre3);
  CALCN(1, hB, bpcB, 0, 0, Bsv4, Bba4, Bre4);
  CALCN(1, hB, bpcB, 0, 1, Bsv5, Bba5, Bre5);
  CALCN(1, hB, bpcB, 1, -1, Bsv6, Bba6, Bre6);
  CALCN(1, hB, bpcB, 1, 0, Bsv7, Bba7, Bre7);
  CALCN(1, hB, bpcB, 1, 1, Bsv8, Bba8, Bre8);
#undef CALCN

  __syncthreads();

  f32x4 accA0 = {0.f, 0.f, 0.f, 0.f}, accA1 = {0.f, 0.f, 0.f, 0.f};
  f32x4 accB0 = {0.f, 0.f, 0.f, 0.f}, accB1 = {0.f, 0.f, 0.f, 0.f};

  // two ping-pong slots of 4 short8 each
  short8 Xa0, Xa1, Xb0, Xb1, Ya0, Ya1, Yb0, Yb1;

#define LOADQ(S, DS0A, BAA, SVA, DS0B, BAB, SVB)                        \
  {                                                                     \
    int d_, o_;                                                         \
    d_ = (DS0A);      o_ = (BAA) + d_ * 40 + vc;                        \
    o_ = ((SVA) && (unsigned)d_ < NB_D) ? o_ : voff_dv;                 \
    S##a0 = *(const short8*)(Sb + o_);                                  \
    d_ = (DS0A) + 16; o_ = (BAA) + d_ * 40 + vc;                        \
    o_ = ((SVA) && (unsigned)d_ < NB_D) ? o_ : voff_dv;                 \
    S##a1 = *(const short8*)(Sb + o_);                                  \
    d_ = (DS0B);      o_ = (BAB) + d_ * 40 + vc;                        \
    o_ = ((SVB) && (unsigned)d_ < NB_D) ? o_ : voff_dv;                 \
    S##b0 = *(const short8*)(Sb + o_);                                  \
    d_ = (DS0B) + 16; o_ = (BAB) + d_ * 40 + vc;                        \
    o_ = ((SVB) && (unsigned)d_ < NB_D) ? o_ : voff_dv;                 \
    S##b1 = *(const short8*)(Sb + o_);                                  \
  }

#define LOAD_U(S, N) \
  LOADQ(S, rA + Are##N, Aba##N, Asv##N, rA + Bre##N, Bba##N, Bsv##N)

#define LOAD_M(S, NE, NO)                                               \
  {                                                                     \
    const int asv = halfbit ? Asv##NO : Asv##NE;                        \
    const int aba = halfbit ? Aba##NO : Aba##NE;                        \
    const int are = halfbit ? Are##NO : Are##NE;                        \
    const int bsv = halfbit ? Bsv##NO : Bsv##NE;                        \
    const int bba = halfbit ? Bba##NO : Bba##NE;                        \
    const int bre = halfbit ? Bre##NO : Bre##NE;                        \
    LOADQ(S, rX + are, aba, asv, rX + bre, bba, bsv)                    \
  }

#define LOAD_M13(S, NE)                                                 \
  {                                                                     \
    const int asv = halfbit ? 0 : Asv##NE;                              \
    const int bsv = halfbit ? 0 : Bsv##NE;                              \
    LOADQ(S, rX + Are##NE, Aba##NE, asv, rX + Bre##NE, Bba##NE, bsv)    \
  }

#define FMA4(P, S)                                                      \
  {                                                                     \
    const short8 bf = bfrag[P];                                         \
    accA0 = __builtin_amdgcn_mfma_f32_16x16x32_bf16(S##a0, bf, accA0, 0, 0, 0); \
    accA1 = __builtin_amdgcn_mfma_f32_16x16x32_bf16(S##a1, bf, accA1, 0, 0, 0); \
    accB0 = __builtin_amdgcn_mfma_f32_16x16x32_bf16(S##b0, bf, accB0, 0, 0, 0); \
    accB1 = __builtin_amdgcn_mfma_f32_16x16x32_bf16(S##b1, bf, accB1, 0, 0, 0); \
  }

  // pipelined: load pair p+1 before consuming pair p
  LOAD_U(X, 0);                    // p0
  LOAD_U(Y, 1);                    // p1
  FMA4(0, X);  LOAD_M(X, 0, 1);    // p2
  FMA4(1, Y);  LOAD_U(Y, 2);       // p3
  FMA4(2, X);  LOAD_U(X, 3);       // p4
  FMA4(3, Y);  LOAD_M(Y, 2, 3);    // p5
  FMA4(4, X);  LOAD_U(X, 4);       // p6
  FMA4(5, Y);  LOAD_U(Y, 5);       // p7
  FMA4(6, X);  LOAD_M(X, 4, 5);    // p8
  FMA4(7, Y);  LOAD_U(Y, 6);       // p9
  FMA4(8, X);  LOAD_U(X, 7);       // p10
  FMA4(9, Y);  LOAD_M(Y, 6, 7);    // p11
  FMA4(10, X); LOAD_U(X, 8);       // p12
  FMA4(11, Y); LOAD_M13(Y, 8);     // p13
  FMA4(12, X);
  FMA4(13, Y);

#undef LOADQ
#undef LOAD_U
#undef LOAD_M
#undef LOAD_M13
#undef FMA4

  // D layout: col = lane&15 (=f), row = grp*4 + reg
  const int obaseA = pixA * (NB_D * NB_F);
  const int obaseB = pixB * (NB_D * NB_F);
#pragma unroll
  for (int rr = 0; rr < 4; ++rr) {
    out[obaseA + (grp * 4 + rr) * NB_F + r] = accA0[rr];
    out[obaseA + (grp * 4 + rr + 16) * NB_F + r] = accA1[rr];
    out[obaseB + (grp * 4 + rr) * NB_F + r] = accB0[rr];
    out[obaseB + (grp * 4 + rr + 16) * NB_F + r] = accB1[rr];
  }
}

// ---------------- fallback (self-contained) if ws is too small -------------
__global__ __launch_bounds__(256) void sconv3d_mfma(
    const float* __restrict__ img, const int* __restrict__ bp,
    const float* __restrict__ kern, const float* __restrict__ dvp,
    float* __restrict__ out, int npix) {
  __shared__ unsigned short Kb[28 * 256];
  const int tid = threadIdx.x;
  for (int idx = tid; idx < 28 * 256; idx += 256) {
    unsigned short v = 0;
    if (idx < 27 * 256) v = (unsigned short)fcvt(kern[idx]);
    Kb[idx] = v;
  }
  __syncthreads();

  const int lane = tid & 63;
  const int grp = lane >> 4;
  const int r = lane & 15;
  const int c0 = (grp & 1) * 8;
  const int half = grp >> 1;

  short8 bfrag[14];
#pragma unroll
  for (int p = 0; p < 14; ++p) {
#pragma unroll
    for (int j = 0; j < 8; ++j) {
      const int k = 8 * grp + j;
      const int t = 2 * p + (k >> 4);
      bfrag[p][j] = (short)Kb[t * 256 + (k & 15) * 16 + r];
    }
  }

  const int pix = blockIdx.x * 4 + (tid >> 6);
  if (pix >= npix) return;
  const int b = pix / (NB_H * NB_W);
  const int rem = pix - b * (NB_H * NB_W);
  const int h = rem >> 7;
  const int w = rem & (NB_W - 1);

  const float dv = dvp[0];
  const int bpc = bp[pix];

  f32x4 acc0 = {0.f, 0.f, 0.f, 0.f};
  f32x4 acc1 = {0.f, 0.f, 0.f, 0.f};

#pragma unroll
  for (int p = 0; p < 14; ++p) {
    const int t = 2 * p + half;
    const int n = t / 3;
    const int kd = t - 3 * n;
    const int i = n / 3;
    const int j = n - 3 * i;
    const int hh = h + i - 1;
    const int ww = w + j - 1;
    const bool sv =
        (t < 27) && (hh >= 0) && (hh < NB_H) && (ww >= 0) && (ww < NB_W);
    const int hc = min(max(hh, 0), NB_H - 1);
    const int wc = min(max(ww, 0), NB_W - 1);
    const int nidx = (b * NB_H + hc) * NB_W + wc;
    const int rel = bpc - bp[nidx];
    const int base = nidx * (NB_D * NB_C);
    const int dsh = (kd - 1) + rel;

    const int ds0 = r + dsh;
    short8 a0;
    {
      float va[8];
      if (sv && (ds0 >= 0) && (ds0 < NB_D)) {
        const float4* pp = (const float4*)(img + base + ds0 * NB_C + c0);
        const float4 x = pp[0];
        const float4 y = pp[1];
        va[0] = x.x; va[1] = x.y; va[2] = x.z; va[3] = x.w;
        va[4] = y.x; va[5] = y.y; va[6] = y.z; va[7] = y.w;
      } else {
#pragma unroll
        for (int q = 0; q < 8; ++q) va[q] = dv;
      }
#pragma unroll
      for (int q = 0; q < 8; ++q) a0[q] = fcvt(va[q]);
    }
    acc0 = __builtin_amdgcn_mfma_f32_16x16x32_bf16(a0, bfrag[p], acc0, 0, 0, 0);

    const int ds1 = ds0 + 16;
    short8 a1;
    {
      float va[8];
      if (sv && (ds1 >= 0) && (ds1 < NB_D)) {
        const float4* pp = (const float4*)(img + base + ds1 * NB_C + c0);
        const float4 x = pp[0];
        const float4 y = pp[1];
        va[0] = x.x; va[1] = x.y; va[2] = x.z; va[3] = x.w;
        va[4] = y.x; va[5] = y.y; va[6] = y.z; va[7] = y.w;
      } else {
#pragma unroll
        for (int q = 0; q < 8; ++q) va[q] = dv;
      }
#pragma unroll
      for (int q = 0; q < 8; ++q) a1[q] = fcvt(va[q]);
    }
    acc1 = __builtin_amdgcn_mfma_f32_16x16x32_bf16(a1, bfrag[p], acc1, 0, 0, 0);
  }

  const int obase = pix * (NB_D * NB_F);
#pragma unroll
  for (int rr = 0; rr < 4; ++rr) {
    out[obase + (grp * 4 + rr) * NB_F + r] = acc0[rr];
    out[obase + (grp * 4 + rr + 16) * NB_F + r] = acc1[rr];
  }
}

extern "C" void kernel_launch(void* const* d_in, const int* in_sizes, int n_in,
                              void* d_out, int out_size, void* d_ws, size_t ws_size,
                              hipStream_t stream) {
  const float* img = (const float*)d_in[0];
  const int* bp = (const int*)d_in[1];
  const float* kern = (const float*)d_in[2];
  const float* dvp = (const float*)d_in[3];
  float* out = (float*)d_out;

  if (ws_size >= WS_NEED) {
    unsigned short* kb2 = (unsigned short*)d_ws;
    sconv3d_wprep<<<28, 256, 0, stream>>>(kern, kb2);
    sconv3d_fused4<<<NPIX / 8, 256, 0, stream>>>(img, bp, kb2, dvp, out);
  } else {
    sconv3d_mfma<<<NPIX / 4, 256, 0, stream>>>(img, bp, kern, dvp, out, NPIX);
  }
}

// Round 12
// 46.817 us; speedup vs baseline: 1.8689x; 1.0075x over previous
//
#include <hip/hip_runtime.h>
#include <hip/hip_bf16.h>

typedef __attribute__((ext_vector_type(8))) short short8;
typedef __attribute__((ext_vector_type(4))) short s16x4;
typedef __attribute__((ext_vector_type(4))) float f32x4;

#define NB_H 96
#define NB_W 128
#define NB_D 32
#define NB_C 16
#define NB_F 16
#define NPIX (2 * NB_H * NB_W)                 // 24576
#define KB2_U16 (14 * 512)                     // 7168 u16 = 14336 B
#define WS_NEED ((size_t)KB2_U16 * 2)
#define SLAB_STRIDE 1280                       // 32 rows * 40 B (32 data + 8 pad)
#define NSLAB 24                               // 4h x 6w (2x4 pixel tile + halo)
#define DV_OFF (NSLAB * SLAB_STRIDE)           // 30720
#define LDS_BYTES (DV_OFF + 64)                // 30784

// fp32 -> bf16 RNE
static __device__ __forceinline__ short fcvt(float f) {
  return (short)__builtin_bit_cast(unsigned short, __float2bfloat16(f));
}

// Pair table: p=3q+m (q=0..3): m=0 -> taps(6q,6q+1) [UNIF n=2q, kd=0/1];
// m=1 -> (6q+3,6q+4) [UNIF n=2q+1]; m=2 -> (6q+2,6q+5) [MIX kd=2].
// p=12 -> (24,25) [UNIF n=8]. p=13 -> (26,pad). tap t = n*3+kd.

// ---- weights prep: kern fp32 -> bf16 B-frag layout [p][grp][f][j] ---------
__global__ __launch_bounds__(256) void sconv3d_wprep(
    const float* __restrict__ kern, unsigned short* __restrict__ kb2) {
  const int i = blockIdx.x * 256 + threadIdx.x;
  if (i >= KB2_U16) return;
  const int p = i >> 9;
  const int g = (i >> 7) & 3;
  const int f = (i >> 3) & 15;
  const int j = i & 7;
  const int k = g * 8 + j;
  int lo, hi;
  if (p < 12) {
    const int q = p / 3, m = p % 3;
    lo = (m == 0) ? 6 * q : (m == 1) ? 6 * q + 3 : 6 * q + 2;
    hi = (m == 0) ? 6 * q + 1 : (m == 1) ? 6 * q + 4 : 6 * q + 5;
  } else if (p == 12) { lo = 24; hi = 25; }
  else { lo = 26; hi = -1; }
  const int t = (k < 16) ? lo : hi;
  const int c = k & 15;
  kb2[i] = (t >= 0) ? (unsigned short)fcvt(kern[(t * 16 + c) * 16 + f])
                    : (unsigned short)0;
}

// ---- fused main: 2x4-px tile, 256 threads, pinned B-frags, 3-slot pipe ----
__global__ __launch_bounds__(256, 3) void sconv3d_fused5(
    const float* __restrict__ img, const int* __restrict__ bp,
    const unsigned short* __restrict__ kb2, const float* __restrict__ dvp,
    float* __restrict__ out) {
  __shared__ char Sb[LDS_BYTES];
  const int tid = threadIdx.x;
  const int lane = tid & 63;
  const int r = lane & 15;          // A: d row; B/D: f column
  const int grp = lane >> 4;        // 0..3
  const int vc = (grp & 1) * 16;    // byte offset of c-slice within 32B row
  const int halfbit = grp >> 1;     // K half: 0 -> tap lo, 1 -> tap hi
  const int rA = r + halfbit - 1;   // depth row pre-rel, kd=(0,1) pairs
  const int rX = r + 1;             // depth row pre-rel, kd=2 pairs
  const int voff_dv = DV_OFF + vc;

  // B-frags: 14 global loads issued first; pinned in VGPRs below
  short8 bfrag[14];
#pragma unroll
  for (int p = 0; p < 14; ++p)
    bfrag[p] = *(const short8*)(kb2 + p * 512 + grp * 128 + r * 8);

  // tile decode, XCD-chunked bijective swizzle: 3072 = 8 * 384
  const int bid = (blockIdx.x & 7) * 384 + (blockIdx.x >> 3);
  const int b = bid >= 1536;                  // 1536 tiles per batch
  const int rem = bid - b * 1536;
  const int h0 = (rem >> 5) * 2;              // 48 h-tiles
  const int w0 = (rem & 31) * 4;              // 32 w-tiles

  // ---- per-wave pixel decode (scalar) ----
  const int wid = __builtin_amdgcn_readfirstlane((int)(tid >> 6));  // 0..3
  const int w = w0 + wid;
  const int hA = h0, hB = h0 + 1;
  const int pixA = (b * NB_H + hA) * NB_W + w;
  const int pixB = pixA + NB_W;
  const int bpcA = bp[pixA];
  const int bpcB = bp[pixB];

#define CALCN(PH, H, BPC, DI, DJ, SV, BA, RE)                           \
  {                                                                     \
    const int hh = (H) + (DI), ww = w + (DJ);                           \
    SV = (hh >= 0) & (hh < NB_H) & (ww >= 0) & (ww < NB_W);             \
    const int hc = min(max(hh, 0), NB_H - 1);                           \
    const int wc = min(max(ww, 0), NB_W - 1);                           \
    RE = (BPC)-bp[(b * NB_H + hc) * NB_W + wc];                         \
    BA = (((PH) + (DI) + 1) * 6 + wid + (DJ) + 1) * SLAB_STRIDE;        \
  }

  int Asv0, Aba0, Are0, Asv1, Aba1, Are1, Asv2, Aba2, Are2;
  int Asv3, Aba3, Are3, Asv4, Aba4, Are4, Asv5, Aba5, Are5;
  int Asv6, Aba6, Are6, Asv7, Aba7, Are7, Asv8, Aba8, Are8;
  int Bsv0, Bba0, Bre0, Bsv1, Bba1, Bre1, Bsv2, Bba2, Bre2;
  int Bsv3, Bba3, Bre3, Bsv4, Bba4, Bre4, Bsv5, Bba5, Bre5;
  int Bsv6, Bba6, Bre6, Bsv7, Bba7, Bre7, Bsv8, Bba8, Bre8;
  CALCN(0, hA, bpcA, -1, -1, Asv0, Aba0, Are0);
  CALCN(0, hA, bpcA, -1, 0, Asv1, Aba1, Are1);
  CALCN(0, hA, bpcA, -1, 1, Asv2, Aba2, Are2);
  CALCN(0, hA, bpcA, 0, -1, Asv3, Aba3, Are3);
  CALCN(0, hA, bpcA, 0, 0, Asv4, Aba4, Are4);
  CALCN(0, hA, bpcA, 0, 1, Asv5, Aba5, Are5);
  CALCN(0, hA, bpcA, 1, -1, Asv6, Aba6, Are6);
  CALCN(0, hA, bpcA, 1, 0, Asv7, Aba7, Are7);
  CALCN(0, hA, bpcA, 1, 1, Asv8, Aba8, Are8);
  CALCN(1, hB, bpcB, -1, -1, Bsv0, Bba0, Bre0);
  CALCN(1, hB, bpcB, -1, 0, Bsv1, Bba1, Bre1);
  CALCN(1, hB, bpcB, -1, 1, Bsv2, Bba2, Bre2);
  CALCN(1, hB, bpcB, 0, -1, Bsv3, Bba3, Bre3);
  CALCN(1, hB, bpcB, 0, 0, Bsv4, Bba4, Bre4);
  CALCN(1, hB, bpcB, 0, 1, Bsv5, Bba5, Bre5);
  CALCN(1, hB, bpcB, 1, -1, Bsv6, Bba6, Bre6);
  CALCN(1, hB, bpcB, 1, 0, Bsv7, Bba7, Bre7);
  CALCN(1, hB, bpcB, 1, 1, Bsv8, Bba8, Bre8);
#undef CALCN

  // ---- stage 24 slabs (4h x 6w, clamped) fp32 -> bf16 -> LDS ----
  const int t2 = tid & 127;
  const int sg = tid >> 7;                    // 0..1
  const int srow = t2 >> 2;                   // d row 0..31
  const int sb8 = (t2 & 3) * 8;               // byte offset in 32B row
#pragma unroll
  for (int pass = 0; pass < 12; ++pass) {
    const int s = pass * 2 + sg;              // slab 0..23
    const int dh = s / 6, dw = s - 6 * dh;
    const int hh = min(max(h0 + dh - 1, 0), NB_H - 1);
    const int ww = min(max(w0 + dw - 1, 0), NB_W - 1);
    const float4 v = *(const float4*)(
        img + ((b * NB_H + hh) * NB_W + ww) * (NB_D * NB_C) + t2 * 4);
    s16x4 o;
    o[0] = fcvt(v.x); o[1] = fcvt(v.y); o[2] = fcvt(v.z); o[3] = fcvt(v.w);
    *(s16x4*)(Sb + s * SLAB_STRIDE + srow * 40 + sb8) = o;
  }
  if (tid < 16) ((unsigned short*)(Sb + DV_OFF))[tid] =
      (unsigned short)fcvt(dvp[0]);

  // pin B-frags: opaque asm output cannot be rematerialized from memory,
  // so the 14 global loads stay hoisted and the values stay in VGPRs
#pragma unroll
  for (int p = 0; p < 14; ++p)
    asm volatile("" : "+v"(bfrag[p]));

  __syncthreads();

  f32x4 accA0 = {0.f, 0.f, 0.f, 0.f}, accA1 = {0.f, 0.f, 0.f, 0.f};
  f32x4 accB0 = {0.f, 0.f, 0.f, 0.f}, accB1 = {0.f, 0.f, 0.f, 0.f};

  // three pipeline slots of 4 short8 each
  short8 Xa0, Xa1, Xb0, Xb1, Ya0, Ya1, Yb0, Yb1, Za0, Za1, Zb0, Zb1;

#define LOADQ(S, DS0A, BAA, SVA, DS0B, BAB, SVB)                        \
  {                                                                     \
    int d_, o_;                                                         \
    d_ = (DS0A);      o_ = (BAA) + d_ * 40 + vc;                        \
    o_ = ((SVA) && (unsigned)d_ < NB_D) ? o_ : voff_dv;                 \
    S##a0 = *(const short8*)(Sb + o_);                                  \
    d_ = (DS0A) + 16; o_ = (BAA) + d_ * 40 + vc;                        \
    o_ = ((SVA) && (unsigned)d_ < NB_D) ? o_ : voff_dv;                 \
    S##a1 = *(const short8*)(Sb + o_);                                  \
    d_ = (DS0B);      o_ = (BAB) + d_ * 40 + vc;                        \
    o_ = ((SVB) && (unsigned)d_ < NB_D) ? o_ : voff_dv;                 \
    S##b0 = *(const short8*)(Sb + o_);                                  \
    d_ = (DS0B) + 16; o_ = (BAB) + d_ * 40 + vc;                        \
    o_ = ((SVB) && (unsigned)d_ < NB_D) ? o_ : voff_dv;                 \
    S##b1 = *(const short8*)(Sb + o_);                                  \
  }

#define LOAD_U(S, N) \
  LOADQ(S, rA + Are##N, Aba##N, Asv##N, rA + Bre##N, Bba##N, Bsv##N)

#define LOAD_M(S, NE, NO)                                               \
  {                                                                     \
    const int asv = halfbit ? Asv##NO : Asv##NE;                        \
    const int aba = halfbit ? Aba##NO : Aba##NE;                        \
    const int are = halfbit ? Are##NO : Are##NE;                        \
    const int bsv = halfbit ? Bsv##NO : Bsv##NE;                        \
    const int bba = halfbit ? Bba##NO : Bba##NE;                        \
    const int bre = halfbit ? Bre##NO : Bre##NE;                        \
    LOADQ(S, rX + are, aba, asv, rX + bre, bba, bsv)                    \
  }

#define LOAD_M13(S, NE)                                                 \
  {                                                                     \
    const int asv = halfbit ? 0 : Asv##NE;                              \
    const int bsv = halfbit ? 0 : Bsv##NE;                              \
    LOADQ(S, rX + Are##NE, Aba##NE, asv, rX + Bre##NE, Bba##NE, bsv)    \
  }

#define FMA4(P, S)                                                      \
  {                                                                     \
    const short8 bf = bfrag[P];                                         \
    accA0 = __builtin_amdgcn_mfma_f32_16x16x32_bf16(S##a0, bf, accA0, 0, 0, 0); \
    accA1 = __builtin_amdgcn_mfma_f32_16x16x32_bf16(S##a1, bf, accA1, 0, 0, 0); \
    accB0 = __builtin_amdgcn_mfma_f32_16x16x32_bf16(S##b0, bf, accB0, 0, 0, 0); \
    accB1 = __builtin_amdgcn_mfma_f32_16x16x32_bf16(S##b1, bf, accB1, 0, 0, 0); \
  }

  // 3-slot pipeline: issue distance = 2 pairs ahead of consumption
  LOAD_U(X, 0);                     // p0
  LOAD_U(Y, 1);                     // p1
  LOAD_M(Z, 0, 1);                  // p2
  FMA4(0, X);  LOAD_U(X, 2);        // p3
  FMA4(1, Y);  LOAD_U(Y, 3);        // p4
  FMA4(2, Z);  LOAD_M(Z, 2, 3);     // p5
  FMA4(3, X);  LOAD_U(X, 4);        // p6
  FMA4(4, Y);  LOAD_U(Y, 5);        // p7
  FMA4(5, Z);  LOAD_M(Z, 4, 5);     // p8
  FMA4(6, X);  LOAD_U(X, 6);        // p9
  FMA4(7, Y);  LOAD_U(Y, 7);        // p10
  FMA4(8, Z);  LOAD_M(Z, 6, 7);     // p11
  FMA4(9, X);  LOAD_U(X, 8);        // p12
  FMA4(10, Y); LOAD_M13(Y, 8);      // p13
  FMA4(11, Z);
  FMA4(12, X);
  FMA4(13, Y);

#undef LOADQ
#undef LOAD_U
#undef LOAD_M
#undef LOAD_M13
#undef FMA4

  // D layout: col = lane&15 (=f), row = grp*4 + reg
  const int obaseA = pixA * (NB_D * NB_F);
  const int obaseB = pixB * (NB_D * NB_F);
#pragma unroll
  for (int rr = 0; rr < 4; ++rr) {
    out[obaseA + (grp * 4 + rr) * NB_F + r] = accA0[rr];
    out[obaseA + (grp * 4 + rr + 16) * NB_F + r] = accA1[rr];
    out[obaseB + (grp * 4 + rr) * NB_F + r] = accB0[rr];
    out[obaseB + (grp * 4 + rr + 16) * NB_F + r] = accB1[rr];
  }
}

// ---------------- fallback (self-contained) if ws is too small -------------
__global__ __launch_bounds__(256) void sconv3d_mfma(
    const float* __restrict__ img, const int* __restrict__ bp,
    const float* __restrict__ kern, const float* __restrict__ dvp,
    float* __restrict__ out, int npix) {
  __shared__ unsigned short Kb[28 * 256];
  const int tid = threadIdx.x;
  for (int idx = tid; idx < 28 * 256; idx += 256) {
    unsigned short v = 0;
    if (idx < 27 * 256) v = (unsigned short)fcvt(kern[idx]);
    Kb[idx] = v;
  }
  __syncthreads();

  const int lane = tid & 63;
  const int grp = lane >> 4;
  const int r = lane & 15;
  const int c0 = (grp & 1) * 8;
  const int half = grp >> 1;

  short8 bfrag[14];
#pragma unroll
  for (int p = 0; p < 14; ++p) {
#pragma unroll
    for (int j = 0; j < 8; ++j) {
      const int k = 8 * grp + j;
      const int t = 2 * p + (k >> 4);
      bfrag[p][j] = (short)Kb[t * 256 + (k & 15) * 16 + r];
    }
  }

  const int pix = blockIdx.x * 4 + (tid >> 6);
  if (pix >= npix) return;
  const int b = pix / (NB_H * NB_W);
  const int rem = pix - b * (NB_H * NB_W);
  const int h = rem >> 7;
  const int w = rem & (NB_W - 1);

  const float dv = dvp[0];
  const int bpc = bp[pix];

  f32x4 acc0 = {0.f, 0.f, 0.f, 0.f};
  f32x4 acc1 = {0.f, 0.f, 0.f, 0.f};

#pragma unroll
  for (int p = 0; p < 14; ++p) {
    const int t = 2 * p + half;
    const int n = t / 3;
    const int kd = t - 3 * n;
    const int i = n / 3;
    const int j = n - 3 * i;
    const int hh = h + i - 1;
    const int ww = w + j - 1;
    const bool sv =
        (t < 27) && (hh >= 0) && (hh < NB_H) && (ww >= 0) && (ww < NB_W);
    const int hc = min(max(hh, 0), NB_H - 1);
    const int wc = min(max(ww, 0), NB_W - 1);
    const int nidx = (b * NB_H + hc) * NB_W + wc;
    const int rel = bpc - bp[nidx];
    const int base = nidx * (NB_D * NB_C);
    const int dsh = (kd - 1) + rel;

    const int ds0 = r + dsh;
    short8 a0;
    {
      float va[8];
      if (sv && (ds0 >= 0) && (ds0 < NB_D)) {
        const float4* pp = (const float4*)(img + base + ds0 * NB_C + c0);
        const float4 x = pp[0];
        const float4 y = pp[1];
        va[0] = x.x; va[1] = x.y; va[2] = x.z; va[3] = x.w;
        va[4] = y.x; va[5] = y.y; va[6] = y.z; va[7] = y.w;
      } else {
#pragma unroll
        for (int q = 0; q < 8; ++q) va[q] = dv;
      }
#pragma unroll
      for (int q = 0; q < 8; ++q) a0[q] = fcvt(va[q]);
    }
    acc0 = __builtin_amdgcn_mfma_f32_16x16x32_bf16(a0, bfrag[p], acc0, 0, 0, 0);

    const int ds1 = ds0 + 16;
    short8 a1;
    {
      float va[8];
      if (sv && (ds1 >= 0) && (ds1 < NB_D)) {
        const float4* pp = (const float4*)(img + base + ds1 * NB_C + c0);
        const float4 x = pp[0];
        const float4 y = pp[1];
        va[0] = x.x; va[1] = x.y; va[2] = x.z; va[3] = x.w;
        va[4] = y.x; va[5] = y.y; va[6] = y.z; va[7] = y.w;
      } else {
#pragma unroll
        for (int q = 0; q < 8; ++q) va[q] = dv;
      }
#pragma unroll
      for (int q = 0; q < 8; ++q) a1[q] = fcvt(va[q]);
    }
    acc1 = __builtin_amdgcn_mfma_f32_16x16x32_bf16(a1, bfrag[p], acc1, 0, 0, 0);
  }

  const int obase = pix * (NB_D * NB_F);
#pragma unroll
  for (int rr = 0; rr < 4; ++rr) {
    out[obase + (grp * 4 + rr) * NB_F + r] = acc0[rr];
    out[obase + (grp * 4 + rr + 16) * NB_F + r] = acc1[rr];
  }
}

extern "C" void kernel_launch(void* const* d_in, const int* in_sizes, int n_in,
                              void* d_out, int out_size, void* d_ws, size_t ws_size,
                              hipStream_t stream) {
  const float* img = (const float*)d_in[0];
  const int* bp = (const int*)d_in[1];
  const float* kern = (const float*)d_in[2];
  const float* dvp = (const float*)d_in[3];
  float* out = (float*)d_out;

  if (ws_size >= WS_NEED) {
    unsigned short* kb2 = (unsigned short*)d_ws;
    sconv3d_wprep<<<28, 256, 0, stream>>>(kern, kb2);
    sconv3d_fused5<<<NPIX / 8, 256, 0, stream>>>(img, bp, kb2, dvp, out);
  } else {
    sconv3d_mfma<<<NPIX / 4, 256, 0, stream>>>(img, bp, kern, dvp, out, NPIX);
  }
}